// Round 3
// baseline (501.154 us; speedup 1.0000x reference)
//
#include <hip/hip_runtime.h>
#include <hip/hip_bf16.h>
#include <stdint.h>

// Problem constants
#define CDIM 256
#define HDIM 128
#define WDIM 128
#define HW   (HDIM * WDIM)     // 16384
#define BATCH 8
#define BUFE  ((size_t)BATCH * CDIM * HW)   // elems per q/k/v buffer

typedef __bf16 bf16;
typedef bf16  bf16x8 __attribute__((ext_vector_type(8)));
typedef float f32x4  __attribute__((ext_vector_type(4)));

#define MFMA16(a, b, c) __builtin_amdgcn_mfma_f32_16x16x32_bf16((a), (b), (c), 0, 0, 0)

// ---------- helpers ----------

// A-operand tile: row-major [rows][ROWelems] bf16, XOR-swizzled: byte col ^= ((row&7)<<4).
// Fragment: lane supplies A[m][k], m = row, k = kelem..kelem+7 (16B contiguous).
__device__ __forceinline__ bf16x8 read_afrag(const bf16* As, int ROWelems, int row, int kelem) {
    const char* base = (const char*)As;
    int cb = (kelem * 2) ^ ((row & 7) << 4);
    return *reinterpret_cast<const bf16x8*>(base + row * ROWelems * 2 + cb);
}

__device__ __forceinline__ void write_a16B(bf16* As, int ROWelems, int row, int colbytes, bf16x8 v) {
    char* base = (char*)As;
    *reinterpret_cast<bf16x8*>(base + row * ROWelems * 2 + (colbytes ^ ((row & 7) << 4))) = v;
}

// B-operand tile: subtiled [K/4][N/16][4][16] (N fixed at 128 -> 8 subtile cols).
// Element (k,n) at ((k>>2)*8 + (n>>4))*64 + (k&3)*16 + (n&15).
__device__ __forceinline__ int bsub_idx(int k, int n) {
    return (((k >> 2) << 3) + (n >> 4)) * 64 + ((k & 3) << 4) + (n & 15);
}

// Scalar-gather B fragment (tr_b16-ready layout; flip to ds_read_b64_tr_b16 later).
// Lane supplies B[k][n]: n = ntile*16 + (lane&15), k = kbase + (lane>>4)*8 + j.
__device__ __forceinline__ bf16x8 read_bfrag(const bf16* Bs, int kbase, int ntile, int lane) {
    int g = lane >> 4;
    int n = (ntile << 4) + (lane & 15);
    int k0 = kbase + (g << 3);
    bf16x8 r;
#pragma unroll
    for (int j = 0; j < 8; ++j) {
        r[j] = Bs[bsub_idx(k0 + j, n)];
    }
    return r;
}

__device__ __forceinline__ bf16x8 cvt8(float4 a, float4 b) {
    bf16x8 v;
    v[0] = (bf16)a.x; v[1] = (bf16)a.y; v[2] = (bf16)a.z; v[3] = (bf16)a.w;
    v[4] = (bf16)b.x; v[5] = (bf16)b.y; v[6] = (bf16)b.z; v[7] = (bf16)b.w;
    return v;
}

// ---------- kernel 1: q/k/v projection (one matrix per blockIdx.y slice) ----------
// out[b, o, p] = sum_c W[o, c] * x[b, c, p] + bias[o], stored bf16 into ws.
// Tile: BM=256 (all o), BN=128 (pixels), BK=64. 512 threads = 8 waves (4 o x 2 p).
__global__ __launch_bounds__(512) void proj_kernel(
    const float* __restrict__ x,
    const float* __restrict__ wq, const float* __restrict__ bq,
    const float* __restrict__ wk, const float* __restrict__ bk,
    const float* __restrict__ wv, const float* __restrict__ bv,
    bf16* __restrict__ qkv)
{
    int pt = blockIdx.x;             // 128 pixel tiles
    int z  = blockIdx.y;             // b*3 + m
    int b = z / 3, m = z - 3 * b;
    const float* Wm = (m == 0) ? wq : (m == 1) ? wk : wv;
    const float* Bm = (m == 0) ? bq : (m == 1) ? bk : bv;
    const float* xb = x + (size_t)b * CDIM * HW;
    bf16* outb = qkv + (size_t)m * BUFE + (size_t)b * CDIM * HW;
    int p0 = pt * 128;

    __shared__ bf16 As[256 * 64];    // W tile, swizzled rows (128B rows)
    __shared__ bf16 Bs[64 * 128];    // x tile, subtiled

    int t = threadIdx.x;
    int wave = t >> 6, lane = t & 63;
    int wm = wave >> 1, wn = wave & 1;

    f32x4 acc[4][4];
#pragma unroll
    for (int i = 0; i < 4; ++i)
#pragma unroll
        for (int j = 0; j < 4; ++j) acc[i][j] = (f32x4){0.f, 0.f, 0.f, 0.f};

    for (int kk = 0; kk < CDIM; kk += 64) {
        // stage W tile: 256 rows x 64 cols fp32 -> bf16 swizzled
#pragma unroll
        for (int pass = 0; pass < 2; ++pass) {
            int row = pass * 128 + (t >> 2);
            int cbe = (t & 3) * 16;  // 16 elems = 64B per thread
            const float4* src = reinterpret_cast<const float4*>(Wm + row * CDIM + kk + cbe);
            float4 f0 = src[0], f1 = src[1], f2 = src[2], f3 = src[3];
            write_a16B(As, 64, row, cbe * 2,      cvt8(f0, f1));
            write_a16B(As, 64, row, cbe * 2 + 16, cvt8(f2, f3));
        }
        // stage x tile: 64 rows (c) x 128 cols (p) fp32 -> bf16 subtiled
        {
            int c  = t >> 3;
            int pb = (t & 7) * 16;
            const float4* src = reinterpret_cast<const float4*>(xb + (size_t)(kk + c) * HW + p0 + pb);
            float4 f0 = src[0], f1 = src[1], f2 = src[2], f3 = src[3];
            int idx = (((c >> 2) << 3) + (pb >> 4)) * 64 + ((c & 3) << 4);
            *reinterpret_cast<bf16x8*>(&Bs[idx])     = cvt8(f0, f1);
            *reinterpret_cast<bf16x8*>(&Bs[idx + 8]) = cvt8(f2, f3);
        }
        __syncthreads();
#pragma unroll
        for (int ks = 0; ks < 64; ks += 32) {
            int ke = ks + ((lane >> 4) << 3);
            bf16x8 af[4], bfr[4];
#pragma unroll
            for (int i = 0; i < 4; ++i)
                af[i] = read_afrag(As, 64, wm * 64 + i * 16 + (lane & 15), ke);
#pragma unroll
            for (int j = 0; j < 4; ++j)
                bfr[j] = read_bfrag(Bs, ks, wn * 4 + j, lane);
#pragma unroll
            for (int i = 0; i < 4; ++i)
#pragma unroll
                for (int j = 0; j < 4; ++j)
                    acc[i][j] = MFMA16(af[i], bfr[j], acc[i][j]);
        }
        __syncthreads();
    }
    // epilogue: bias + bf16 store
#pragma unroll
    for (int i = 0; i < 4; ++i) {
#pragma unroll
        for (int r = 0; r < 4; ++r) {
            int o = wm * 64 + i * 16 + ((lane >> 4) << 2) + r;
            float bias = Bm[o];
#pragma unroll
            for (int j = 0; j < 4; ++j) {
                int p = p0 + wn * 64 + j * 16 + (lane & 15);
                outb[(size_t)o * HW + p] = (bf16)(acc[i][j][r] + bias);
            }
        }
    }
}

// ---------- kernel 2: per-channel attention ----------
// One block per (b, c). Q,K,V are contiguous [128][128] bf16 blocks.
// S = (Q K^T) * 32^-0.25, softmax rows, O = softmax(S) V, O overwrites q buffer.
__global__ __launch_bounds__(512) void attn_kernel(bf16* __restrict__ qkv)
{
    int bc = blockIdx.x;             // 0..2047
    size_t blk = (size_t)bc * HW;
    bf16* qb       = qkv + blk;                 // also output
    const bf16* kb = qkv + BUFE + blk;
    const bf16* vb = qkv + 2 * BUFE + blk;

    __shared__ bf16 Qs[128 * 128];   // swizzled rows (256B rows)
    __shared__ bf16 Ks[128 * 128];   // swizzled rows
    __shared__ bf16 Vs[128 * 128];   // subtiled
    __shared__ bf16 Ps[128 * 128];   // swizzled rows; wave-private row ranges

    int t = threadIdx.x;
    int wave = t >> 6, lane = t & 63;

    // stage Q, K (swizzled) and V (subtiled)
    {
        int row = t >> 2;
        int cb  = (t & 3) * 32;      // 32 elems = 64B per thread per array
        const uint4* qsrc = reinterpret_cast<const uint4*>(qb + (size_t)row * WDIM + cb);
        const uint4* ksrc = reinterpret_cast<const uint4*>(kb + (size_t)row * WDIM + cb);
        const uint4* vsrc = reinterpret_cast<const uint4*>(vb + (size_t)row * WDIM + cb);
        char* qdst = (char*)Qs + row * 256;
        char* kdst = (char*)Ks + row * 256;
        int sw = (row & 7) << 4;
#pragma unroll
        for (int u = 0; u < 4; ++u) {
            int off = cb * 2 + u * 16;
            *reinterpret_cast<uint4*>(qdst + (off ^ sw)) = qsrc[u];
            *reinterpret_cast<uint4*>(kdst + (off ^ sw)) = ksrc[u];
        }
#pragma unroll
        for (int u = 0; u < 4; ++u) {
            int e = cb + u * 8;
            int idx = (((row >> 2) << 3) + (e >> 4)) * 64 + ((row & 3) << 4) + (e & 8);
            *reinterpret_cast<uint4*>(&Vs[idx]) = vsrc[u];
        }
    }
    __syncthreads();

    // QK^T: wave handles S rows [wave*16, wave*16+16)
    f32x4 sacc[8];
#pragma unroll
    for (int j = 0; j < 8; ++j) sacc[j] = (f32x4){0.f, 0.f, 0.f, 0.f};
#pragma unroll
    for (int ks = 0; ks < 128; ks += 32) {
        int ke = ks + ((lane >> 4) << 3);
        bf16x8 aq = read_afrag(Qs, 128, (wave << 4) + (lane & 15), ke);
#pragma unroll
        for (int j = 0; j < 8; ++j) {
            bf16x8 bk8 = read_afrag(Ks, 128, (j << 4) + (lane & 15), ke);
            sacc[j] = MFMA16(aq, bk8, sacc[j]);
        }
    }

    // softmax (fp32): scale, row-max, exp, row-sum; write unnormalized P (<=1) to LDS
    // Reference: q *= HEAD_DIM**-0.25 (only q, contraction axis is W) -> logit scale 32^-0.25
    const float SCALE_QK = 0.42044820762685725f; // 32^-0.25
    float rinv[4];
#pragma unroll
    for (int r = 0; r < 4; ++r) {
        float mx = -1e30f;
#pragma unroll
        for (int j = 0; j < 8; ++j) {
            sacc[j][r] *= SCALE_QK;
            mx = fmaxf(mx, sacc[j][r]);
        }
#pragma unroll
        for (int d = 1; d < 16; d <<= 1) mx = fmaxf(mx, __shfl_xor(mx, d));
        float sum = 0.f;
#pragma unroll
        for (int j = 0; j < 8; ++j) {
            float e = __expf(sacc[j][r] - mx);
            sacc[j][r] = e;
            sum += e;
        }
#pragma unroll
        for (int d = 1; d < 16; d <<= 1) sum += __shfl_xor(sum, d);
        rinv[r] = 1.0f / sum;
        int row = (wave << 4) + ((lane >> 4) << 2) + r;
        char* pdst = (char*)Ps + row * 256;
        int swp = (row & 7) << 4;
#pragma unroll
        for (int j = 0; j < 8; ++j) {
            int colb = ((j << 4) + (lane & 15)) * 2;
            *reinterpret_cast<bf16*>(pdst + (colb ^ swp)) = (bf16)sacc[j][r];
        }
    }
    // wave-private P rows: no __syncthreads needed (same-wave LDS ordering)

    // O = P V  (normalize in epilogue with rinv; rinv rows == oacc reg rows)
    f32x4 oacc[8];
#pragma unroll
    for (int j = 0; j < 8; ++j) oacc[j] = (f32x4){0.f, 0.f, 0.f, 0.f};
#pragma unroll
    for (int ks = 0; ks < 128; ks += 32) {
        int ke = ks + ((lane >> 4) << 3);
        bf16x8 ap = read_afrag(Ps, 128, (wave << 4) + (lane & 15), ke);
#pragma unroll
        for (int j = 0; j < 8; ++j) {
            bf16x8 bv8 = read_bfrag(Vs, ks, j, lane);
            oacc[j] = MFMA16(ap, bv8, oacc[j]);
        }
    }
#pragma unroll
    for (int r = 0; r < 4; ++r) {
        int xrow = (wave << 4) + ((lane >> 4) << 2) + r;
#pragma unroll
        for (int j = 0; j < 8; ++j) {
            qb[(size_t)xrow * WDIM + (j << 4) + (lane & 15)] = (bf16)(oacc[j][r] * rinv[r]);
        }
    }
}

// ---------- kernel 3: output projection ----------
// out[b, o, p] = sum_c Wo[o, c] * ao[b, c, p] + bo[o]   (ao = attn output, bf16; out fp32)
__global__ __launch_bounds__(512) void outproj_kernel(
    const bf16* __restrict__ ao, const float* __restrict__ Wo,
    const float* __restrict__ bo, float* __restrict__ out)
{
    int pt = blockIdx.x, b = blockIdx.y;
    const bf16* aob = ao + (size_t)b * CDIM * HW;
    float* outb = out + (size_t)b * CDIM * HW;
    int p0 = pt * 128;

    __shared__ bf16 As[256 * 64];
    __shared__ bf16 Bs[64 * 128];

    int t = threadIdx.x;
    int wave = t >> 6, lane = t & 63;
    int wm = wave >> 1, wn = wave & 1;

    f32x4 acc[4][4];
#pragma unroll
    for (int i = 0; i < 4; ++i)
#pragma unroll
        for (int j = 0; j < 4; ++j) acc[i][j] = (f32x4){0.f, 0.f, 0.f, 0.f};

    for (int kk = 0; kk < CDIM; kk += 64) {
#pragma unroll
        for (int pass = 0; pass < 2; ++pass) {
            int row = pass * 128 + (t >> 2);
            int cbe = (t & 3) * 16;
            const float4* src = reinterpret_cast<const float4*>(Wo + row * CDIM + kk + cbe);
            float4 f0 = src[0], f1 = src[1], f2 = src[2], f3 = src[3];
            write_a16B(As, 64, row, cbe * 2,      cvt8(f0, f1));
            write_a16B(As, 64, row, cbe * 2 + 16, cvt8(f2, f3));
        }
        {
            int c  = t >> 3;
            int pb = (t & 7) * 16;
            const uint4* src = reinterpret_cast<const uint4*>(aob + (size_t)(kk + c) * HW + p0 + pb);
            uint4 v0 = src[0], v1 = src[1];
            int idx = (((c >> 2) << 3) + (pb >> 4)) * 64 + ((c & 3) << 4);
            *reinterpret_cast<uint4*>(&Bs[idx])     = v0;
            *reinterpret_cast<uint4*>(&Bs[idx + 8]) = v1;
        }
        __syncthreads();
#pragma unroll
        for (int ks = 0; ks < 64; ks += 32) {
            int ke = ks + ((lane >> 4) << 3);
            bf16x8 af[4], bfr[4];
#pragma unroll
            for (int i = 0; i < 4; ++i)
                af[i] = read_afrag(As, 64, wm * 64 + i * 16 + (lane & 15), ke);
#pragma unroll
            for (int j = 0; j < 4; ++j)
                bfr[j] = read_bfrag(Bs, ks, wn * 4 + j, lane);
#pragma unroll
            for (int i = 0; i < 4; ++i)
#pragma unroll
                for (int j = 0; j < 4; ++j)
                    acc[i][j] = MFMA16(af[i], bfr[j], acc[i][j]);
        }
        __syncthreads();
    }
#pragma unroll
    for (int i = 0; i < 4; ++i) {
#pragma unroll
        for (int r = 0; r < 4; ++r) {
            int o = wm * 64 + i * 16 + ((lane >> 4) << 2) + r;
            float bias = bo[o];
#pragma unroll
            for (int j = 0; j < 4; ++j) {
                int p = p0 + wn * 64 + j * 16 + (lane & 15);
                outb[(size_t)o * HW + p] = acc[i][j][r] + bias;
            }
        }
    }
}

// ---------- launch ----------
extern "C" void kernel_launch(void* const* d_in, const int* in_sizes, int n_in,
                              void* d_out, int out_size, void* d_ws, size_t ws_size,
                              hipStream_t stream) {
    const float* x  = (const float*)d_in[0];
    const float* wq = (const float*)d_in[1];
    const float* bq = (const float*)d_in[2];
    const float* wk = (const float*)d_in[3];
    const float* bk = (const float*)d_in[4];
    const float* wv = (const float*)d_in[5];
    const float* bv = (const float*)d_in[6];
    const float* wo = (const float*)d_in[7];
    const float* bo = (const float*)d_in[8];
    float* out = (float*)d_out;
    bf16* qkv = (bf16*)d_ws;   // needs 3 * 8*256*16384 * 2B = 192 MiB

    proj_kernel<<<dim3(128, 24), 512, 0, stream>>>(x, wq, bq, wk, bk, wv, bv, qkv);
    attn_kernel<<<dim3(2048), 512, 0, stream>>>(qkv);
    outproj_kernel<<<dim3(128, 8), 512, 0, stream>>>(qkv, wo, bo, out);
}

// Round 4
// 488.753 us; speedup vs baseline: 1.0254x; 1.0254x over previous
//
#include <hip/hip_runtime.h>
#include <hip/hip_bf16.h>
#include <stdint.h>

// Problem constants
#define CDIM 256
#define HDIM 128
#define WDIM 128
#define HW   (HDIM * WDIM)     // 16384
#define BATCH 8
#define BUFE  ((size_t)BATCH * CDIM * HW)   // elems per q/k/v buffer

typedef __bf16 bf16;
typedef bf16  bf16x8 __attribute__((ext_vector_type(8)));
typedef bf16  bf16x4 __attribute__((ext_vector_type(4)));
typedef unsigned short u16x4 __attribute__((ext_vector_type(4)));
typedef unsigned short u16x8 __attribute__((ext_vector_type(8)));
typedef float f32x4  __attribute__((ext_vector_type(4)));

#define MFMA16(a, b, c) __builtin_amdgcn_mfma_f32_16x16x32_bf16((a), (b), (c), 0, 0, 0)

// ---------- helpers ----------

// A-operand tile: row-major [rows][ROWelems] bf16, XOR-swizzled: byte col ^= ((row&7)<<4).
// Fragment: lane supplies A[m][k], m = row, k = kelem..kelem+7 (16B contiguous).
__device__ __forceinline__ bf16x8 read_afrag(const bf16* As, int ROWelems, int row, int kelem) {
    const char* base = (const char*)As;
    int cb = (kelem * 2) ^ ((row & 7) << 4);
    return *reinterpret_cast<const bf16x8*>(base + row * ROWelems * 2 + cb);
}

__device__ __forceinline__ void write_a16B(bf16* As, int ROWelems, int row, int colbytes, bf16x8 v) {
    char* base = (char*)As;
    *reinterpret_cast<bf16x8*>(base + row * ROWelems * 2 + (colbytes ^ ((row & 7) << 4))) = v;
}

// Transposed-staged tiles (xT[p][c], VT[w][y]): refined swizzle mixing row bit 3
// so both the 4-stride transposing writer and the 16-consecutive-row reader spread banks.
__device__ __forceinline__ int swt(int row) {
    return ((row ^ (row >> 3)) & 7) << 4;
}
__device__ __forceinline__ bf16x8 read_tfrag(const bf16* Ts, int ROWelems, int row, int kelem) {
    const char* base = (const char*)Ts;
    int cb = (kelem * 2) ^ swt(row);
    return *reinterpret_cast<const bf16x8*>(base + row * ROWelems * 2 + cb);
}
__device__ __forceinline__ void write_t8B(bf16* Ts, int ROWelems, int row, int colbytes, u16x4 v) {
    char* base = (char*)Ts;
    *reinterpret_cast<u16x4*>(base + row * ROWelems * 2 + (colbytes ^ swt(row))) = v;
}

__device__ __forceinline__ bf16x8 cvt8(float4 a, float4 b) {
    bf16x8 v;
    v[0] = (bf16)a.x; v[1] = (bf16)a.y; v[2] = (bf16)a.z; v[3] = (bf16)a.w;
    v[4] = (bf16)b.x; v[5] = (bf16)b.y; v[6] = (bf16)b.z; v[7] = (bf16)b.w;
    return v;
}

__device__ __forceinline__ unsigned short bfbits(float f) {
    bf16 h = (bf16)f;
    return __builtin_bit_cast(unsigned short, h);
}

// ---------- kernel 1: q/k/v projection ----------
// out[b, o, p] = sum_c W[o, c] * x[b, c, p] + bias[o], stored bf16 into ws.
// Tile: BM=256 (all o), BN=128 (pixels), BK=64. 512 threads = 8 waves (4 o x 2 p).
// B-tile staged TRANSPOSED (xT[p][c]) via in-register 4x4 transpose -> b128 frag reads.
__global__ __launch_bounds__(512) void proj_kernel(
    const float* __restrict__ x,
    const float* __restrict__ wq, const float* __restrict__ bq,
    const float* __restrict__ wk, const float* __restrict__ bk,
    const float* __restrict__ wv, const float* __restrict__ bv,
    bf16* __restrict__ qkv)
{
    int pt = blockIdx.x;             // 128 pixel tiles
    int z  = blockIdx.y;             // b*3 + m
    int b = z / 3, m = z - 3 * b;
    const float* Wm = (m == 0) ? wq : (m == 1) ? wk : wv;
    const float* Bm = (m == 0) ? bq : (m == 1) ? bk : bv;
    const float* xb = x + (size_t)b * CDIM * HW;
    bf16* outb = qkv + (size_t)m * BUFE + (size_t)b * CDIM * HW;
    int p0 = pt * 128;

    __shared__ bf16 As[256 * 64];    // W tile, swizzled rows (128B rows)
    __shared__ bf16 Bs[128 * 64];    // xT tile: [p][c], 128B rows, swt-swizzled

    int t = threadIdx.x;
    int wave = t >> 6, lane = t & 63;
    int wm = wave >> 1, wn = wave & 1;

    f32x4 acc[4][4];
#pragma unroll
    for (int i = 0; i < 4; ++i)
#pragma unroll
        for (int j = 0; j < 4; ++j) acc[i][j] = (f32x4){0.f, 0.f, 0.f, 0.f};

    for (int kk = 0; kk < CDIM; kk += 64) {
        // stage W tile: 256 rows x 64 cols fp32 -> bf16 swizzled
#pragma unroll
        for (int pass = 0; pass < 2; ++pass) {
            int row = pass * 128 + (t >> 2);
            int cbe = (t & 3) * 16;  // 16 elems = 64B per thread
            const float4* src = reinterpret_cast<const float4*>(Wm + row * CDIM + kk + cbe);
            float4 f0 = src[0], f1 = src[1], f2 = src[2], f3 = src[3];
            write_a16B(As, 64, row, cbe * 2,      cvt8(f0, f1));
            write_a16B(As, 64, row, cbe * 2 + 16, cvt8(f2, f3));
        }
        // stage x tile TRANSPOSED: read 4c x 4p fp32, in-reg transpose, write b64s.
        // pb fast across lanes -> global reads 32x16B contiguous (512B) per quarter-wave.
        {
            int pb = t & 31;         // p = pb*4
            int cb = t >> 5;         // c = cb*4 (0..60)
            int p = pb * 4, c = cb * 4;
            float4 f[4];
#pragma unroll
            for (int r = 0; r < 4; ++r)
                f[r] = *reinterpret_cast<const float4*>(xb + (size_t)(kk + c + r) * HW + p0 + p);
#pragma unroll
            for (int i = 0; i < 4; ++i) {
                u16x4 v;
                v[0] = bfbits(((const float*)&f[0])[i]);
                v[1] = bfbits(((const float*)&f[1])[i]);
                v[2] = bfbits(((const float*)&f[2])[i]);
                v[3] = bfbits(((const float*)&f[3])[i]);
                write_t8B(Bs, 64, p + i, c * 2, v);
            }
        }
        __syncthreads();
#pragma unroll
        for (int ks = 0; ks < 64; ks += 32) {
            int ke = ks + ((lane >> 4) << 3);
            bf16x8 af[4], bfr[4];
#pragma unroll
            for (int i = 0; i < 4; ++i)
                af[i] = read_afrag(As, 64, wm * 64 + i * 16 + (lane & 15), ke);
#pragma unroll
            for (int j = 0; j < 4; ++j)
                bfr[j] = read_tfrag(Bs, 64, wn * 64 + j * 16 + (lane & 15), ke);
#pragma unroll
            for (int i = 0; i < 4; ++i)
#pragma unroll
                for (int j = 0; j < 4; ++j)
                    acc[i][j] = MFMA16(af[i], bfr[j], acc[i][j]);
        }
        __syncthreads();
    }
    // epilogue: bias + bf16 store
#pragma unroll
    for (int i = 0; i < 4; ++i) {
#pragma unroll
        for (int r = 0; r < 4; ++r) {
            int o = wm * 64 + i * 16 + ((lane >> 4) << 2) + r;
            float bias = Bm[o];
#pragma unroll
            for (int j = 0; j < 4; ++j) {
                int p = p0 + wn * 64 + j * 16 + (lane & 15);
                outb[(size_t)o * HW + p] = (bf16)(acc[i][j][r] + bias);
            }
        }
    }
}

// ---------- kernel 2: per-channel attention ----------
// One block per (b, c). Q,K,V are contiguous [128][128] bf16 blocks.
// S = (Q K^T) * 32^-0.25, softmax rows, O = softmax(S) V, O overwrites q buffer.
// V staged TRANSPOSED (VT[w][y]) -> PV B-frags are b128 reads.
__global__ __launch_bounds__(512) void attn_kernel(bf16* __restrict__ qkv)
{
    int bc = blockIdx.x;             // 0..2047
    size_t blk = (size_t)bc * HW;
    bf16* qb       = qkv + blk;                 // also output
    const bf16* kb = qkv + BUFE + blk;
    const bf16* vb = qkv + 2 * BUFE + blk;

    __shared__ bf16 Qs[128 * 128];   // swizzled rows (256B rows)
    __shared__ bf16 Ks[128 * 128];   // swizzled rows
    __shared__ bf16 Vs[128 * 128];   // VT[w][y], 256B rows, swt-swizzled
    __shared__ bf16 Ps[128 * 128];   // swizzled rows; wave-private row ranges

    int t = threadIdx.x;
    int wave = t >> 6, lane = t & 63;

    // stage Q, K (row-major swizzled)
    {
        int row = t >> 2;
        int cb  = (t & 3) * 32;      // 32 elems = 64B per thread per array
        const uint4* qsrc = reinterpret_cast<const uint4*>(qb + (size_t)row * WDIM + cb);
        const uint4* ksrc = reinterpret_cast<const uint4*>(kb + (size_t)row * WDIM + cb);
        char* qdst = (char*)Qs + row * 256;
        char* kdst = (char*)Ks + row * 256;
        int sw = (row & 7) << 4;
#pragma unroll
        for (int u = 0; u < 4; ++u) {
            int off = cb * 2 + u * 16;
            *reinterpret_cast<uint4*>(qdst + (off ^ sw)) = qsrc[u];
            *reinterpret_cast<uint4*>(kdst + (off ^ sw)) = ksrc[u];
        }
    }
    // stage V transposed: read 4y x 8w bf16, in-reg transpose, write b64s.
    // yb fast across lanes -> LDS write banks spread via y; global reads strided but L2/L3-resident.
    {
        int yb = t & 31;             // y0 = yb*4
        int wb = t >> 5;             // w0 = wb*8
        int y0 = yb * 4, w0 = wb * 8;
        u16x8 rv[4];
#pragma unroll
        for (int r = 0; r < 4; ++r)
            rv[r] = *reinterpret_cast<const u16x8*>(vb + (size_t)(y0 + r) * WDIM + w0);
#pragma unroll
        for (int i = 0; i < 8; ++i) {
            u16x4 v;
            v[0] = rv[0][i]; v[1] = rv[1][i]; v[2] = rv[2][i]; v[3] = rv[3][i];
            write_t8B(Vs, 128, w0 + i, y0 * 2, v);
        }
    }
    __syncthreads();

    // QK^T: wave handles S rows [wave*16, wave*16+16)
    f32x4 sacc[8];
#pragma unroll
    for (int j = 0; j < 8; ++j) sacc[j] = (f32x4){0.f, 0.f, 0.f, 0.f};
#pragma unroll
    for (int ks = 0; ks < 128; ks += 32) {
        int ke = ks + ((lane >> 4) << 3);
        bf16x8 aq = read_afrag(Qs, 128, (wave << 4) + (lane & 15), ke);
#pragma unroll
        for (int j = 0; j < 8; ++j) {
            bf16x8 bk8 = read_afrag(Ks, 128, (j << 4) + (lane & 15), ke);
            sacc[j] = MFMA16(aq, bk8, sacc[j]);
        }
    }

    // softmax (fp32): scale, row-max, exp, row-sum; write unnormalized P (<=1) to LDS
    // Reference: q *= HEAD_DIM**-0.25 (only q, contraction axis is W) -> logit scale 32^-0.25
    const float SCALE_QK = 0.42044820762685725f; // 32^-0.25
    float rinv[4];
#pragma unroll
    for (int r = 0; r < 4; ++r) {
        float mx = -1e30f;
#pragma unroll
        for (int j = 0; j < 8; ++j) {
            sacc[j][r] *= SCALE_QK;
            mx = fmaxf(mx, sacc[j][r]);
        }
#pragma unroll
        for (int d = 1; d < 16; d <<= 1) mx = fmaxf(mx, __shfl_xor(mx, d));
        float sum = 0.f;
#pragma unroll
        for (int j = 0; j < 8; ++j) {
            float e = __expf(sacc[j][r] - mx);
            sacc[j][r] = e;
            sum += e;
        }
#pragma unroll
        for (int d = 1; d < 16; d <<= 1) sum += __shfl_xor(sum, d);
        rinv[r] = 1.0f / sum;
        int row = (wave << 4) + ((lane >> 4) << 2) + r;
        char* pdst = (char*)Ps + row * 256;
        int swp = (row & 7) << 4;
#pragma unroll
        for (int j = 0; j < 8; ++j) {
            int colb = ((j << 4) + (lane & 15)) * 2;
            *reinterpret_cast<bf16*>(pdst + (colb ^ swp)) = (bf16)sacc[j][r];
        }
    }
    // wave-private P rows: no __syncthreads needed (same-wave LDS ordering)

    // O = P V  (normalize in epilogue with rinv; rinv rows == oacc reg rows)
    f32x4 oacc[8];
#pragma unroll
    for (int j = 0; j < 8; ++j) oacc[j] = (f32x4){0.f, 0.f, 0.f, 0.f};
#pragma unroll
    for (int ks = 0; ks < 128; ks += 32) {
        int ke = ks + ((lane >> 4) << 3);
        bf16x8 ap = read_afrag(Ps, 128, (wave << 4) + (lane & 15), ke);
#pragma unroll
        for (int j = 0; j < 8; ++j) {
            bf16x8 bv8 = read_tfrag(Vs, 128, (j << 4) + (lane & 15), ke);
            oacc[j] = MFMA16(ap, bv8, oacc[j]);
        }
    }
#pragma unroll
    for (int r = 0; r < 4; ++r) {
        int xrow = (wave << 4) + ((lane >> 4) << 2) + r;
#pragma unroll
        for (int j = 0; j < 8; ++j) {
            qb[(size_t)xrow * WDIM + (j << 4) + (lane & 15)] = (bf16)(oacc[j][r] * rinv[r]);
        }
    }
}

// ---------- kernel 3: output projection ----------
// out[b, o, p] = sum_c Wo[o, c] * ao[b, c, p] + bo[o]   (ao = attn output, bf16; out fp32)
__global__ __launch_bounds__(512) void outproj_kernel(
    const bf16* __restrict__ ao, const float* __restrict__ Wo,
    const float* __restrict__ bo, float* __restrict__ out)
{
    int pt = blockIdx.x, b = blockIdx.y;
    const bf16* aob = ao + (size_t)b * CDIM * HW;
    float* outb = out + (size_t)b * CDIM * HW;
    int p0 = pt * 128;

    __shared__ bf16 As[256 * 64];
    __shared__ bf16 Bs[128 * 64];    // aoT tile: [p][c], swt-swizzled

    int t = threadIdx.x;
    int wave = t >> 6, lane = t & 63;
    int wm = wave >> 1, wn = wave & 1;

    f32x4 acc[4][4];
#pragma unroll
    for (int i = 0; i < 4; ++i)
#pragma unroll
        for (int j = 0; j < 4; ++j) acc[i][j] = (f32x4){0.f, 0.f, 0.f, 0.f};

    for (int kk = 0; kk < CDIM; kk += 64) {
#pragma unroll
        for (int pass = 0; pass < 2; ++pass) {
            int row = pass * 128 + (t >> 2);
            int cbe = (t & 3) * 16;
            const float4* src = reinterpret_cast<const float4*>(Wo + row * CDIM + kk + cbe);
            float4 f0 = src[0], f1 = src[1], f2 = src[2], f3 = src[3];
            write_a16B(As, 64, row, cbe * 2,      cvt8(f0, f1));
            write_a16B(As, 64, row, cbe * 2 + 16, cvt8(f2, f3));
        }
        // stage ao tile TRANSPOSED: read 4c x 4p bf16 (b64 loads), transpose, b64 writes
        {
            int pb = t & 31;         // p = pb*4
            int cb = t >> 5;         // c = cb*4
            int p = pb * 4, c = cb * 4;
            u16x4 rv[4];
#pragma unroll
            for (int r = 0; r < 4; ++r)
                rv[r] = *reinterpret_cast<const u16x4*>(aob + (size_t)(kk + c + r) * HW + p0 + p);
#pragma unroll
            for (int i = 0; i < 4; ++i) {
                u16x4 v;
                v[0] = rv[0][i]; v[1] = rv[1][i]; v[2] = rv[2][i]; v[3] = rv[3][i];
                write_t8B(Bs, 64, p + i, c * 2, v);
            }
        }
        __syncthreads();
#pragma unroll
        for (int ks = 0; ks < 64; ks += 32) {
            int ke = ks + ((lane >> 4) << 3);
            bf16x8 af[4], bfr[4];
#pragma unroll
            for (int i = 0; i < 4; ++i)
                af[i] = read_afrag(As, 64, wm * 64 + i * 16 + (lane & 15), ke);
#pragma unroll
            for (int j = 0; j < 4; ++j)
                bfr[j] = read_tfrag(Bs, 64, wn * 64 + j * 16 + (lane & 15), ke);
#pragma unroll
            for (int i = 0; i < 4; ++i)
#pragma unroll
                for (int j = 0; j < 4; ++j)
                    acc[i][j] = MFMA16(af[i], bfr[j], acc[i][j]);
        }
        __syncthreads();
    }
#pragma unroll
    for (int i = 0; i < 4; ++i) {
#pragma unroll
        for (int r = 0; r < 4; ++r) {
            int o = wm * 64 + i * 16 + ((lane >> 4) << 2) + r;
            float bias = bo[o];
#pragma unroll
            for (int j = 0; j < 4; ++j) {
                int p = p0 + wn * 64 + j * 16 + (lane & 15);
                outb[(size_t)o * HW + p] = acc[i][j][r] + bias;
            }
        }
    }
}

// ---------- launch ----------
extern "C" void kernel_launch(void* const* d_in, const int* in_sizes, int n_in,
                              void* d_out, int out_size, void* d_ws, size_t ws_size,
                              hipStream_t stream) {
    const float* x  = (const float*)d_in[0];
    const float* wq = (const float*)d_in[1];
    const float* bq = (const float*)d_in[2];
    const float* wk = (const float*)d_in[3];
    const float* bk = (const float*)d_in[4];
    const float* wv = (const float*)d_in[5];
    const float* bv = (const float*)d_in[6];
    const float* wo = (const float*)d_in[7];
    const float* bo = (const float*)d_in[8];
    float* out = (float*)d_out;
    bf16* qkv = (bf16*)d_ws;   // needs 3 * 8*256*16384 * 2B = 192 MiB

    proj_kernel<<<dim3(128, 24), 512, 0, stream>>>(x, wq, bq, wk, bk, wv, bv, qkv);
    attn_kernel<<<dim3(2048), 512, 0, stream>>>(qkv);
    outproj_kernel<<<dim3(128, 8), 512, 0, stream>>>(qkv, wo, bo, out);
}